// Round 1
// baseline (239.168 us; speedup 1.0000x reference)
//
#include <hip/hip_runtime.h>
#include <cstddef>

// Problem constants
static constexpr int B = 32;
static constexpr int N = 1024;

// ---------------------------------------------------------------------------
// Transpose X [B][N][8] -> xb [B][8][N]  (so layer loads are coalesced)
// ---------------------------------------------------------------------------
__global__ __launch_bounds__(256) void transpose_x_k(const float* __restrict__ X,
                                                     float* __restrict__ xb) {
    int i = blockIdx.x * 256 + threadIdx.x;   // over B*N*8 = 262144
    int b = i >> 13;                          // /8192
    int rem = i & 8191;
    int n = rem >> 3;
    int f = rem & 7;
    xb[((size_t)b << 13) + f * N + n] = X[i];
}

// ---------------------------------------------------------------------------
// One GCN layer: xout = tanh(adj[b] @ (xin[b] @ W))
// xin  [B][FIN][N]  (transposed), xout [B][FOUT][N]
// grid: B * (N/16) blocks of 256 threads; each block = 16 rows; each wave = 4.
// ---------------------------------------------------------------------------
template <int FIN, int FOUT>
__global__ __launch_bounds__(256) void layer_k(const float* __restrict__ xin,
                                               const float* __restrict__ adj,
                                               const float* __restrict__ W,
                                               float* __restrict__ xout) {
    __shared__ float y[FOUT][N];

    const int b  = blockIdx.x >> 6;          // 64 row-blocks per batch
    const int n0 = (blockIdx.x & 63) << 4;   // *16 rows

    // ---- y = xin[b] @ W  (computed cooperatively into LDS, [FOUT][N]) ----
    float w[FIN][FOUT];
#pragma unroll
    for (int fi = 0; fi < FIN; ++fi)
#pragma unroll
        for (int f = 0; f < FOUT; ++f) w[fi][f] = W[fi * FOUT + f];

    {
        const int m4 = threadIdx.x << 2;     // 256 threads * 4 = 1024
        const float* xbp = xin + (size_t)b * FIN * N + m4;
        float4 xv[FIN];
#pragma unroll
        for (int fi = 0; fi < FIN; ++fi)
            xv[fi] = *(const float4*)(xbp + fi * N);
#pragma unroll
        for (int f = 0; f < FOUT; ++f) {
            float4 a = make_float4(0.f, 0.f, 0.f, 0.f);
#pragma unroll
            for (int fi = 0; fi < FIN; ++fi) {
                a.x += xv[fi].x * w[fi][f];
                a.y += xv[fi].y * w[fi][f];
                a.z += xv[fi].z * w[fi][f];
                a.w += xv[fi].w * w[fi][f];
            }
            *(float4*)&y[f][m4] = a;
        }
    }
    __syncthreads();

    // ---- rows: acc[r][f] = sum_m adj[b][n][m] * y[f][m] ----
    const int wave = threadIdx.x >> 6;
    const int lane = threadIdx.x & 63;
    const int nb   = n0 + (wave << 2);       // 4 rows per wave
    const float* adjb = adj + (size_t)b * N * N;

    float acc[4][FOUT];
#pragma unroll
    for (int r = 0; r < 4; ++r)
#pragma unroll
        for (int f = 0; f < FOUT; ++f) acc[r][f] = 0.f;

#pragma unroll
    for (int k = 0; k < 4; ++k) {
        const int m = k * 256 + (lane << 2);
        float4 a4[4];
#pragma unroll
        for (int r = 0; r < 4; ++r)
            a4[r] = *(const float4*)(adjb + (size_t)(nb + r) * N + m);
#pragma unroll
        for (int f = 0; f < FOUT; ++f) {
            const float4 yv = *(const float4*)&y[f][m];
#pragma unroll
            for (int r = 0; r < 4; ++r)
                acc[r][f] += a4[r].x * yv.x + a4[r].y * yv.y +
                             a4[r].z * yv.z + a4[r].w * yv.w;
        }
    }

    // ---- 64-lane butterfly reduce each accumulator ----
#pragma unroll
    for (int r = 0; r < 4; ++r)
#pragma unroll
        for (int f = 0; f < FOUT; ++f) {
            float v = acc[r][f];
#pragma unroll
            for (int off = 32; off >= 1; off >>= 1)
                v += __shfl_xor(v, off, 64);
            acc[r][f] = v;
        }

    // ---- write: lane -> (r, f), statically-selected value ----
    if (lane < 4 * FOUT) {
        const int r = lane / FOUT;
        const int f = lane - r * FOUT;
        float v = 0.f;
#pragma unroll
        for (int rr = 0; rr < 4; ++rr)
#pragma unroll
            for (int ff = 0; ff < FOUT; ++ff)
                if (rr == r && ff == f) v = acc[rr][ff];
        xout[((size_t)b * FOUT + f) * N + nb + r] = tanhf(v);
    }
}

// ---------------------------------------------------------------------------
// Fused mu/lv heads + reparameterization.
// x6 [B][2][N]; writes z @0, z_mean @32768, z_log_var @65536 of out.
// ---------------------------------------------------------------------------
__global__ __launch_bounds__(256) void muvl_k(const float* __restrict__ x6,
                                              const float* __restrict__ adj,
                                              const float* __restrict__ eps,
                                              const float* __restrict__ Wmu,
                                              const float* __restrict__ Wlv,
                                              float* __restrict__ out) {
    __shared__ float y[2][N];

    const int b  = blockIdx.x >> 6;
    const int n0 = (blockIdx.x & 63) << 4;

    const float wm0 = Wmu[0], wm1 = Wmu[1];
    const float wl0 = Wlv[0], wl1 = Wlv[1];

    {
        const int m4 = threadIdx.x << 2;
        const float* xp = x6 + (size_t)b * 2 * N;
        float4 x0 = *(const float4*)(xp + m4);
        float4 x1 = *(const float4*)(xp + N + m4);
        float4 ym, yl;
        ym.x = x0.x * wm0 + x1.x * wm1;  ym.y = x0.y * wm0 + x1.y * wm1;
        ym.z = x0.z * wm0 + x1.z * wm1;  ym.w = x0.w * wm0 + x1.w * wm1;
        yl.x = x0.x * wl0 + x1.x * wl1;  yl.y = x0.y * wl0 + x1.y * wl1;
        yl.z = x0.z * wl0 + x1.z * wl1;  yl.w = x0.w * wl0 + x1.w * wl1;
        *(float4*)&y[0][m4] = ym;
        *(float4*)&y[1][m4] = yl;
    }
    __syncthreads();

    const int wave = threadIdx.x >> 6;
    const int lane = threadIdx.x & 63;
    const int nb   = n0 + (wave << 2);
    const float* adjb = adj + (size_t)b * N * N;

    float am[4] = {0.f, 0.f, 0.f, 0.f};
    float al[4] = {0.f, 0.f, 0.f, 0.f};

#pragma unroll
    for (int k = 0; k < 4; ++k) {
        const int m = k * 256 + (lane << 2);
        const float4 ym4 = *(const float4*)&y[0][m];
        const float4 yl4 = *(const float4*)&y[1][m];
#pragma unroll
        for (int r = 0; r < 4; ++r) {
            const float4 a4 = *(const float4*)(adjb + (size_t)(nb + r) * N + m);
            am[r] += a4.x * ym4.x + a4.y * ym4.y + a4.z * ym4.z + a4.w * ym4.w;
            al[r] += a4.x * yl4.x + a4.y * yl4.y + a4.z * yl4.z + a4.w * yl4.w;
        }
    }

#pragma unroll
    for (int r = 0; r < 4; ++r) {
        float vm = am[r], vl = al[r];
#pragma unroll
        for (int off = 32; off >= 1; off >>= 1) {
            vm += __shfl_xor(vm, off, 64);
            vl += __shfl_xor(vl, off, 64);
        }
        am[r] = vm; al[r] = vl;
    }

    if (lane < 4) {
        const int r = lane;
        float zm = 0.f, zlv = 0.f;
#pragma unroll
        for (int rr = 0; rr < 4; ++rr)
            if (rr == r) { zm = am[rr]; zlv = al[rr]; }
        const int n = nb + r;
        const float e = eps[b * N + n];
        const float z = zm + e * expf(0.5f * zlv);
        out[b * N + n]          = z;
        out[32768 + b * N + n]  = zm;
        out[65536 + b * N + n]  = zlv;
    }
}

// ---------------------------------------------------------------------------
// adj_pred[b][n][m] = z[b][n] * z[b][m]   (pure streaming write)
// grid = B*N blocks; each block writes one 1024-float row as float4s.
// ---------------------------------------------------------------------------
__global__ __launch_bounds__(256) void adjpred_k(const float* __restrict__ z,
                                                 float* __restrict__ out) {
    const int b = blockIdx.x >> 10;
    const int n = blockIdx.x & 1023;
    const float zn = z[b * N + n];
    const int m4 = threadIdx.x << 2;
    const float4 zm4 = *(const float4*)(z + b * N + m4);
    float4 o;
    o.x = zn * zm4.x; o.y = zn * zm4.y; o.z = zn * zm4.z; o.w = zn * zm4.w;
    *(float4*)(out + ((size_t)b << 20) + ((size_t)n << 10) + m4) = o;
}

// ---------------------------------------------------------------------------
extern "C" void kernel_launch(void* const* d_in, const int* in_sizes, int n_in,
                              void* d_out, int out_size, void* d_ws, size_t ws_size,
                              hipStream_t stream) {
    const float* X   = (const float*)d_in[0];
    const float* adj = (const float*)d_in[1];
    const float* eps = (const float*)d_in[2];
    const float* W0  = (const float*)d_in[3];
    const float* W1  = (const float*)d_in[4];
    const float* W2  = (const float*)d_in[5];
    const float* W3  = (const float*)d_in[6];
    const float* W4  = (const float*)d_in[7];
    const float* W5  = (const float*)d_in[8];
    const float* Wmu = (const float*)d_in[9];
    const float* Wlv = (const float*)d_in[10];

    float* out = (float*)d_out;
    float* x0  = (float*)d_ws;            // [B][8][N] = 262144 floats
    float* x1  = x0 + (size_t)B * 8 * N;  // second ping-pong buffer

    transpose_x_k<<<1024, 256, 0, stream>>>(X, x0);

    layer_k<8, 7><<<2048, 256, 0, stream>>>(x0, adj, W0, x1);
    layer_k<7, 6><<<2048, 256, 0, stream>>>(x1, adj, W1, x0);
    layer_k<6, 5><<<2048, 256, 0, stream>>>(x0, adj, W2, x1);
    layer_k<5, 4><<<2048, 256, 0, stream>>>(x1, adj, W3, x0);
    layer_k<4, 3><<<2048, 256, 0, stream>>>(x0, adj, W4, x1);
    layer_k<3, 2><<<2048, 256, 0, stream>>>(x1, adj, W5, x0);

    muvl_k<<<2048, 256, 0, stream>>>(x0, adj, eps, Wmu, Wlv, out);

    adjpred_k<<<B * N, 256, 0, stream>>>(out, out + 3 * 32768);
}